// Round 12
// baseline (595.212 us; speedup 1.0000x reference)
//
#include <hip/hip_runtime.h>

typedef unsigned short ushort_t;
typedef __attribute__((ext_vector_type(8))) __bf16 bf16x8;
typedef __attribute__((ext_vector_type(4))) float f32x4;
typedef __attribute__((ext_vector_type(4))) int i32x4;
typedef __attribute__((ext_vector_type(4))) unsigned short u16x4;
typedef __attribute__((ext_vector_type(8))) unsigned short u16x8;

__device__ __forceinline__ float bf2f(ushort_t u) {
  union { unsigned u32; float f; } c; c.u32 = ((unsigned)u) << 16; return c.f;
}
__device__ __forceinline__ ushort_t f2bf(float f) {
  union { float f; unsigned u32; } c; c.f = f;
  unsigned u = c.u32;
  u += 0x7fffu + ((u >> 16) & 1u);
  return (ushort_t)(u >> 16);
}

__device__ __forceinline__ void gload_lds16(const void* g, void* l) {
  __builtin_amdgcn_global_load_lds(
      (const __attribute__((address_space(1))) void*)g,
      (__attribute__((address_space(3))) void*)l,
      16, 0, 0);
}

// 512-thread stager: one 128x64 bf16 half-tile (2 gloads/thread)
__device__ __forceinline__ void stage_half(const char* gbase, long row0, int ldbytes,
                                           int kbyte, char* lds_half, int tid)
{
  const int rl = tid >> 3;
  const int cs = ((tid & 7) ^ (rl & 7)) << 4;
  const char* g0 = gbase + (row0 + rl) * (long)ldbytes + kbyte + cs;
  char* l0 = lds_half + ((tid >> 6) << 10);
  gload_lds16(g0, l0);
  gload_lds16(g0 + (long)ldbytes * 64, l0 + 8192);
}

// 256-thread stager: one 128x64 bf16 half-tile (4 gloads/thread, rows +32)
__device__ __forceinline__ void stage128(const char* gbase, long row0, int ldbytes,
                                         int kbyte, char* lds_buf, int tid)
{
  const int rl = tid >> 3;                 // 0..31
  const int w = tid >> 6;                  // wave 0..3
#pragma unroll
  for (int k = 0; k < 4; ++k) {
    const int row = rl + k * 32;
    const int cs = ((tid & 7) ^ (row & 7)) << 4;   // row&7 == rl&7
    const char* g0 = gbase + (row0 + row) * (long)ldbytes + kbyte + cs;
    gload_lds16(g0, lds_buf + k * 4096 + w * 1024);
  }
}

#define BAR() __builtin_amdgcn_s_barrier()
#define VMW6() asm volatile("s_waitcnt vmcnt(6)" ::: "memory")
#define VMW16() asm volatile("s_waitcnt vmcnt(16)" ::: "memory")
#define LGKM0() asm volatile("s_waitcnt lgkmcnt(0)" ::: "memory")
#define PR1() __builtin_amdgcn_s_setprio(1)
#define PR0() __builtin_amdgcn_s_setprio(0)

// 16x16x32 fragment reads (conflict-free: per-16-lane group XOR key g)
#define RD_A4(dst, base, rb) \
  _Pragma("unroll") for (int m_ = 0; m_ < 4; ++m_) { \
    const char* p_ = (base) + ((rb) + m_ * 16 + fr) * 128; \
    dst[m_][0] = *(const bf16x8*)(p_ + ch0); \
    dst[m_][1] = *(const bf16x8*)(p_ + ch1); }
#define RD_B2(dst, base, cb) \
  _Pragma("unroll") for (int n_ = 0; n_ < 2; ++n_) { \
    const char* p_ = (base) + ((cb) + n_ * 16 + fr) * 128; \
    dst[n_][0] = *(const bf16x8*)(p_ + ch0); \
    dst[n_][1] = *(const bf16x8*)(p_ + ch1); }

// ===========================================================================
// gemm256: 256x256 bf16 NT GEMM. FOUR waves (2x2), wave tile 128x128 --
// halves LDS fragment traffic per FLOP vs the 8-wave 2x4 layout (the measured
// 41% MfmaUtil ceiling). 1 wave/SIMD -> 512-VGPR budget (acc 256 + frags).
// BK=64 double-buffered; counted vmcnt(16); barriers only at buffer handoff.
// ===========================================================================
#define Q_RA(dst, base) \
  _Pragma("unroll") for (int m_ = 0; m_ < 8; ++m_) { \
    const char* p_ = (base) + (wrb + m_ * 16 + fr) * 128; \
    dst[m_][0] = *(const bf16x8*)(p_ + ch0); \
    dst[m_][1] = *(const bf16x8*)(p_ + ch1); }
#define Q_RB(dst, base, cb) \
  _Pragma("unroll") for (int n_ = 0; n_ < 4; ++n_) { \
    const char* p_ = (base) + ((cb) + n_ * 16 + fr) * 128; \
    dst[n_][0] = *(const bf16x8*)(p_ + ch0); \
    dst[n_][1] = *(const bf16x8*)(p_ + ch1); }
#define Q_MM(jb, Bb) \
  _Pragma("unroll") for (int m_ = 0; m_ < 8; ++m_) \
  _Pragma("unroll") for (int n_ = 0; n_ < 4; ++n_) \
  _Pragma("unroll") for (int s_ = 0; s_ < 2; ++s_) \
    acc[m_][(jb) + n_] = __builtin_amdgcn_mfma_f32_16x16x32_bf16( \
        aF[m_][s_], Bb[n_][s_], acc[m_][(jb) + n_], 0, 0, 0);
#define STGA(t, buf) do { stage128(gA, m0, ldab, (t) << 7, (buf), tid); \
    stage128(gA, m0 + 128, ldab, (t) << 7, (buf) + 16384, tid); } while (0)
#define STGB(t, buf) do { stage128(gB, n0, ldbb, (t) << 7, (buf), tid); \
    stage128(gB, n0 + 128, ldbb, (t) << 7, (buf) + 16384, tid); } while (0)

template<int EPI, int MAPQ, bool ROUTE>
__global__ __launch_bounds__(256, 1) void gemm256(
    const ushort_t* __restrict__ A, int lda,
    const ushort_t* __restrict__ B, int ldb,
    ushort_t* __restrict__ C0, ushort_t* __restrict__ C1, ushort_t* __restrict__ C2,
    int ldc, const float* __restrict__ bias, float scale, int K)
{
  __shared__ __attribute__((aligned(16))) ushort_t lds[65536];

  int bx, by;
  if (MAPQ == 1) {
    const int flat = blockIdx.y * 4 + blockIdx.x;       // grid 4x64
    by = ((flat >> 5) << 3) | (flat & 7);
    bx = (flat >> 3) & 3;
  } else if (MAPQ == 2) {                               // fused QKV grid 768
    const int l = blockIdx.x;
    const int c = l & 7, u = l >> 3;
    const int q12 = u / 12;
    by = (q12 << 3) | c;
    bx = u - q12 * 12;
  } else { bx = blockIdx.x; by = blockIdx.y; }

  const int NT = K >> 6, NIT = NT >> 1, NTm1 = NT - 1;

  const int tid = threadIdx.x, lane = tid & 63;
  const int fr = lane & 15, g = lane >> 4, lm = lane & 7;
  const int wv = tid >> 6;                 // 0..3
  const int wr = wv >> 1, wc = wv & 1;     // 2x2 wave grid
  const int wrb = wr << 7, wcb = wc << 7;  // 128x128 wave tiles
  const long m0 = (long)by << 8, n0 = (long)bx << 8;

  const char* gA = (const char*)A;
  const char* gB = (const char*)B;
  const int ldab = lda << 1, ldbb = ldb << 1;

  const int ch0 = (g ^ lm) << 4;
  const int ch1 = ((4 | g) ^ lm) << 4;

  char* AE = (char*)lds;
  char* AO = AE + 32768;
  char* BE = AE + 65536;
  char* BO = AE + 98304;

  f32x4 acc[8][8] = {};
  bf16x8 aF[8][2], bX[4][2], bY[4][2];

  // prologue: stage T0 (16 loads) + T1 (16 loads); vmcnt(16) -> T0 landed
  STGA(0, AE); STGB(0, BE);
  STGA(1, AO); STGB(1, BO);
  VMW16(); BAR();

  for (int i = 0; i < NIT; ++i) {
    const int t2 = (2 * i + 2 < NTm1) ? 2 * i + 2 : NTm1;
    const int t3 = (2 * i + 3 < NTm1) ? 2 * i + 3 : NTm1;

    // tile e (bufE)
    Q_RA(aF, AE);
    Q_RB(bX, BE, wcb);
    PR1(); Q_MM(0, bX); PR0();
    Q_RB(bY, BE, wcb + 64);
    PR1(); Q_MM(4, bY); PR0();
    LGKM0(); BAR();                  // all bufE reads complete everywhere
    STGA(t2, AE); STGB(t2, BE);      // overwrite bufE
    VMW16(); BAR();                  // drains T(o) loads -> bufO published
    // tile o (bufO)
    Q_RA(aF, AO);
    Q_RB(bX, BO, wcb);
    PR1(); Q_MM(0, bX); PR0();
    Q_RB(bY, BO, wcb + 64);
    PR1(); Q_MM(4, bY); PR0();
    LGKM0(); BAR();
    STGA(t3, AO); STGB(t3, BO);
    VMW16(); BAR();                  // drains T(t2) -> bufE published
  }

  ushort_t* Cd = C0;
  long nc0 = (long)bx << 8;
  if constexpr (ROUTE) {
    const int which = bx >> 2;
    Cd = (which == 0) ? C0 : (which == 1) ? C1 : C2;
    nc0 = (long)(bx & 3) << 8;
  }

  const int cm = g << 2, cn = fr;
#pragma unroll
  for (int i2 = 0; i2 < 8; ++i2)
#pragma unroll
    for (int j2 = 0; j2 < 8; ++j2) {
      const long gm = m0 + wrb + i2 * 16 + cm;
      const long gn = nc0 + wcb + j2 * 16 + cn;
      float bv = 0.f;
      if constexpr (EPI >= 1) bv = bias[gn];
#pragma unroll
      for (int r = 0; r < 4; ++r) {
        float v = acc[i2][j2][r] * scale + bv;
        if constexpr (EPI == 2) v = fmaxf(v, 0.f);
        Cd[(gm + r) * ldc + gn] = f2bf(v);
      }
    }
}

// ===========================================================================
// gemmA: 256x128 bf16 NT GEMM, region-pipelined, triple-buffered LDS (144 KiB),
// counted vmcnt(6), 8 waves (4Mx2N), wave 64x64, 512 threads. (unchanged)
// MAP: 1 = triangular scores (576 blocks, bz=bid&7), 2 = heavy-first PV (512).
// ===========================================================================
#define A_MM(jb, Aa, Bb) \
  _Pragma("unroll") for (int m_ = 0; m_ < 4; ++m_) \
  _Pragma("unroll") for (int n_ = 0; n_ < 2; ++n_) \
  _Pragma("unroll") for (int s_ = 0; s_ < 2; ++s_) \
    acc[m_][(jb) + n_] = __builtin_amdgcn_mfma_f32_16x16x32_bf16( \
        Aa[m_][s_], Bb[n_][s_], acc[m_][(jb) + n_], 0, 0, 0);
#define SAA_(t, hh, dst) stage_half(gA, m0 + (hh) * 128, ldab, (t) << 7, (dst) + (hh) * 16384, tid)
#define SBA_(t, dst) stage_half(gB, n0, ldbb, (t) << 7, (dst), tid)

template<int EPI, int MAP, bool CKLIM>
__global__ __launch_bounds__(512, 1) void gemmA(
    const ushort_t* __restrict__ A, int lda, long bsA,
    const ushort_t* __restrict__ B, int ldb, long bsB,
    ushort_t* __restrict__ C, int ldc, long bsC,
    const float* __restrict__ bias, float scale, int K)
{
  __shared__ __attribute__((aligned(16))) ushort_t lds[73728];  // 144 KiB

  int bx, by, bz;
  if (MAP == 1) {
    const int bid = blockIdx.x;
    bz = bid & 7; const int r = bid >> 3;
    by = 0; while ((by + 1) * (by + 2) <= r) ++by;
    bx = r - by * (by + 1);
  } else if (MAP == 2) {
    const int bid = blockIdx.x;
    bz = bid & 7; const int u = bid >> 3;
    by = 7 - (u >> 3); bx = u & 7;
  } else { bx = blockIdx.x; by = blockIdx.y; bz = blockIdx.z; }

  const int NT = CKLIM ? ((by + 1) << 2) : (K >> 6);
  const int NIT = NT >> 1, NTm1 = NT - 1;   // NT always even here

  const int tid = threadIdx.x, lane = tid & 63;
  const int fr = lane & 15, g = lane >> 4, lm = lane & 7;
  const int wv = tid >> 6, wr4 = wv >> 1, wc2 = wv & 1;
  const int wrb = wr4 << 6, wcb = wc2 << 6;
  const long m0 = (long)by << 8, n0 = (long)bx << 7;

  const char* gA = (const char*)(A + bz * bsA);
  const char* gB = (const char*)(B + bz * bsB);
  const int ldab = lda << 1, ldbb = ldb << 1;

  const int ch0 = (g ^ lm) << 4;
  const int ch1 = ((4 | g) ^ lm) << 4;

  // roles: pE holds tile e, pO tile o=e+1, pS spare (receives tile e+2)
  char* pEA = (char*)lds;          char* pEB = pEA + 32768;
  char* pOA = (char*)lds + 49152;  char* pOB = pOA + 32768;
  char* pSA = (char*)lds + 98304;  char* pSB = pSA + 32768;

  f32x4 acc[4][4] = {};
  bf16x8 aE[4][2], aO[4][2], bLE[2][2], bLO[2][2], bH[2][2];

  // prologue: stage T0 (6), T1 (6); vmcnt(6) -> T0 landed; read e-frags
  SAA_(0, 0, pEA); SAA_(0, 1, pEA); SBA_(0, pEB);
  SAA_(1, 0, pOA); SAA_(1, 1, pOA); SBA_(1, pOB);
  VMW6(); BAR();
  RD_A4(aE, pEA, wrb); RD_B2(bLE, pEB, wcb);

  for (int i = 0; i < NIT; ++i) {
    const int t2 = (2 * i + 2 < NTm1) ? 2 * i + 2 : NTm1;
    const int t3 = (2 * i + 3 < NTm1) ? 2 * i + 3 : NTm1;

    // region A: tile e; stage t2 -> spare (dead buffer, no hazard)
    PR1(); A_MM(0, aE, bLE); PR0();
    RD_B2(bH, pEB, wcb + 32);
    SAA_(t2, 0, pSA); SAA_(t2, 1, pSA); SBA_(t2, pSB);
    PR1(); A_MM(2, aE, bH); PR0();
    LGKM0(); VMW6(); BAR();               // lgkm: pE reads done; vmcnt drains tile o
    // region B: tile o; stage t3 -> pE (protected by barrier above)
    RD_A4(aO, pOA, wrb); RD_B2(bLO, pOB, wcb);
    PR1(); A_MM(0, aO, bLO); PR0();
    RD_B2(bH, pOB, wcb + 32);
    SAA_(t3, 0, pEA); SAA_(t3, 1, pEA); SBA_(t3, pEB);
    PR1(); A_MM(2, aO, bH); PR0();
    LGKM0(); VMW6(); BAR();               // lgkm: pO reads done; vmcnt drains t2
    RD_A4(aE, pSA, wrb); RD_B2(bLE, pSB, wcb);
    // rotate roles: (E,O,S) <- (S,E,O)
    char* tA = pEA; pEA = pSA; pSA = pOA; pOA = tA;
    char* tB = pEB; pEB = pSB; pSB = pOB; pOB = tB;
  }

  ushort_t* Cb = C + bz * bsC;
  const int cm = g << 2, cn = fr;
#pragma unroll
  for (int i2 = 0; i2 < 4; ++i2)
#pragma unroll
    for (int j2 = 0; j2 < 4; ++j2) {
      const long gm = m0 + wrb + i2 * 16 + cm;
      const long gn = n0 + wcb + j2 * 16 + cn;
      float bv = 0.f;
      if constexpr (EPI >= 1) bv = bias[gn];
#pragma unroll
      for (int r = 0; r < 4; ++r) {
        float v = acc[i2][j2][r] * scale + bv;
        if constexpr (EPI == 2) v = fmaxf(v, 0.f);
        Cb[(gm + r) * ldc + gn] = f2bf(v);
      }
    }
}

// ---------------------------------------------------------------------------
// 64x64 bf16 transpose: Vt[d][s] = V[s][d]
// ---------------------------------------------------------------------------
__global__ __launch_bounds__(256) void transpose_bf16(
    const ushort_t* __restrict__ V, int ldv, long bsV,
    ushort_t* __restrict__ Vt, int ldt, long bsT)
{
  __shared__ __attribute__((aligned(16))) ushort_t tile[64][72];
  const int bz = blockIdx.z;
  const ushort_t* Vb = V + bz * bsV;
  ushort_t* Tb = Vt + bz * bsT;
  const long s0 = (long)blockIdx.y << 6;
  const long d0 = (long)blockIdx.x << 6;
  const int tid = threadIdx.x;
  const int r = tid >> 3, c = tid & 7;
#pragma unroll
  for (int hh = 0; hh < 2; ++hh) {
    const int rr = r + hh * 32;
    i32x4 v = *(const i32x4*)(Vb + (s0 + rr) * ldv + d0 + c * 8);
    *(i32x4*)&tile[rr][c * 8] = v;
  }
  __syncthreads();
#pragma unroll
  for (int hh = 0; hh < 2; ++hh) {
    const int dr = r + hh * 32;
    union { ushort_t u[8]; i32x4 v; } t;
#pragma unroll
    for (int j = 0; j < 8; ++j) t.u[j] = tile[c * 8 + j][dr];
    *(i32x4*)(Tb + (d0 + dr) * ldt + s0 + c * 8) = t.v;
  }
}

// ---------------------------------------------------------------------------
// Row softmax, register-resident, TWO complementary rows per block.
// ---------------------------------------------------------------------------
__global__ __launch_bounds__(256) void softmax_sit2(ushort_t* __restrict__ S,
                                                    const float* __restrict__ sit)
{
  __shared__ float redA[4], redB[4];
  const int bid = blockIdx.x;               // 0..8191
  const long rowA = bid, rowB = 16383 - bid;
  const int bA = (int)(rowA >> 11), tA = (int)(rowA & 2047);
  const int bB = (int)(rowB >> 11), tB = (int)(rowB & 2047);
  const int nA = tA + 1, nB = tB + 1;
  const int rupA = ((tA >> 8) + 1) << 8, rupB = ((tB >> 8) + 1) << 8;
  ushort_t* SrA = S + (rowA << 11);
  ushort_t* SrB = S + (rowB << 11);
  const int tid = threadIdx.x;
  const int i0 = tid << 3;
  const bool actA = i0 < rupA, actB = i0 < rupB;

  u16x8 rawA = {}, rawB = {};
  if (actA) rawA = *(const u16x8*)(SrA + i0);
  if (actB) rawB = *(const u16x8*)(SrB + i0);
  float vA[8], vB[8];
#pragma unroll
  for (int j = 0; j < 8; ++j) { vA[j] = bf2f(rawA[j]); vB[j] = bf2f(rawB[j]); }

  float mA = -3.0e38f, mB = -3.0e38f;
#pragma unroll
  for (int j = 0; j < 8; ++j) {
    if (i0 + j < nA) mA = fmaxf(mA, vA[j]);
    if (i0 + j < nB) mB = fmaxf(mB, vB[j]);
  }
#pragma unroll
  for (int o = 32; o > 0; o >>= 1) {
    mA = fmaxf(mA, __shfl_down(mA, o, 64));
    mB = fmaxf(mB, __shfl_down(mB, o, 64));
  }
  if ((tid & 63) == 0) { redA[tid >> 6] = mA; redB[tid >> 6] = mB; }
  __syncthreads();
  const float mxA = fmaxf(fmaxf(redA[0], redA[1]), fmaxf(redA[2], redA[3]));
  const float mxB = fmaxf(fmaxf(redB[0], redB[1]), fmaxf(redB[2], redB[3]));
  __syncthreads();

  float eA[8], eB[8];
  float sA = 0.f, sB = 0.f;
#pragma unroll
  for (int j = 0; j < 8; ++j) {
    eA[j] = (i0 + j < nA) ? __expf(vA[j] - mxA) : 0.f;
    eB[j] = (i0 + j < nB) ? __expf(vB[j] - mxB) : 0.f;
    sA += eA[j]; sB += eB[j];
  }
#pragma unroll
  for (int o = 32; o > 0; o >>= 1) {
    sA += __shfl_down(sA, o, 64);
    sB += __shfl_down(sB, o, 64);
  }
  if ((tid & 63) == 0) { redA[tid >> 6] = sA; redB[tid >> 6] = sB; }
  __syncthreads();
  const float lA = redA[0] + redA[1] + redA[2] + redA[3];
  const float lB = redB[0] + redB[1] + redB[2] + redB[3];

  float invA = 1.f / lA, invB = 1.f / lB;
  if (sit[rowA] == 0.f) invA = 0.f;
  if (sit[rowB] == 0.f) invB = 0.f;
  if (actA) {
    const float* sb = sit + ((long)bA << 11) + i0;
    u16x8 out;
#pragma unroll
    for (int j = 0; j < 8; ++j)
      out[j] = f2bf((i0 + j < nA && sb[j] != 0.f) ? eA[j] * invA : 0.f);
    *(u16x8*)(SrA + i0) = out;
  }
  if (actB) {
    const float* sb = sit + ((long)bB << 11) + i0;
    u16x8 out;
#pragma unroll
    for (int j = 0; j < 8; ++j)
      out[j] = f2bf((i0 + j < nB && sb[j] != 0.f) ? eB[j] * invB : 0.f);
    *(u16x8*)(SrB + i0) = out;
  }
}

// ---------------------------------------------------------------------------
// out = LN(xin + res) * g + b ; D = 1024, one block per row
// ---------------------------------------------------------------------------
template<bool RES_F32, bool OUT_F32>
__global__ __launch_bounds__(256) void resid_ln(
    const ushort_t* __restrict__ xin, const void* __restrict__ resv,
    const float* __restrict__ g, const float* __restrict__ be, void* __restrict__ outv)
{
  __shared__ float red[4];
  const long base = (long)blockIdx.x << 10;
  const int tid = threadIdx.x;
  const int i0 = tid << 2;

  const u16x4 xa = *(const u16x4*)(xin + base + i0);
  float v[4];
  if constexpr (RES_F32) {
    const float4 rv = *(const float4*)((const float*)resv + base + i0);
    v[0] = bf2f(xa.x) + rv.x; v[1] = bf2f(xa.y) + rv.y;
    v[2] = bf2f(xa.z) + rv.z; v[3] = bf2f(xa.w) + rv.w;
  } else {
    const u16x4 rb = *(const u16x4*)((const ushort_t*)resv + base + i0);
    v[0] = bf2f(xa.x) + bf2f(rb.x); v[1] = bf2f(xa.y) + bf2f(rb.y);
    v[2] = bf2f(xa.z) + bf2f(rb.z); v[3] = bf2f(xa.w) + bf2f(rb.w);
  }
  float s = v[0] + v[1] + v[2] + v[3];
#pragma unroll
  for (int o = 32; o > 0; o >>= 1) s += __shfl_down(s, o, 64);
  if ((tid & 63) == 0) red[tid >> 6] = s;
  __syncthreads();
  const float mu = (red[0] + red[1] + red[2] + red[3]) * (1.f / 1024.f);
  __syncthreads();
  float s2 = 0.f;
#pragma unroll
  for (int j = 0; j < 4; ++j) { const float d = v[j] - mu; s2 += d * d; }
#pragma unroll
  for (int o = 32; o > 0; o >>= 1) s2 += __shfl_down(s2, o, 64);
  if ((tid & 63) == 0) red[tid >> 6] = s2;
  __syncthreads();
  const float rstd = rsqrtf((red[0] + red[1] + red[2] + red[3]) * (1.f / 1024.f) + 1e-5f);

  const float4 gv = *(const float4*)(g + i0);
  const float4 bv = *(const float4*)(be + i0);
  const float o0 = (v[0] - mu) * rstd * gv.x + bv.x;
  const float o1 = (v[1] - mu) * rstd * gv.y + bv.y;
  const float o2 = (v[2] - mu) * rstd * gv.z + bv.z;
  const float o3 = (v[3] - mu) * rstd * gv.w + bv.w;
  if constexpr (OUT_F32) {
    float4 ov; ov.x = o0; ov.y = o1; ov.z = o2; ov.w = o3;
    *(float4*)((float*)outv + base + i0) = ov;
  } else {
    u16x4 ob = { f2bf(o0), f2bf(o1), f2bf(o2), f2bf(o3) };
    *(u16x4*)((ushort_t*)outv + base + i0) = ob;
  }
}

__global__ __launch_bounds__(256) void cast_f32_bf16(const float* __restrict__ src,
                                                     ushort_t* __restrict__ dst, int n4)
{
  const int i = blockIdx.x * 256 + threadIdx.x;
  if (i >= n4) return;
  const float4 v = *(const float4*)(src + ((long)i << 2));
  u16x4 o = { f2bf(v.x), f2bf(v.y), f2bf(v.z), f2bf(v.w) };
  *(u16x4*)(dst + ((long)i << 2)) = o;
}

__global__ __launch_bounds__(256) void cast_w5(
    const float* __restrict__ s0, const float* __restrict__ s1,
    const float* __restrict__ s2, const float* __restrict__ s3,
    const float* __restrict__ s4, ushort_t* __restrict__ dst)
{
  const int w = blockIdx.y;
  const float* src = (w == 0) ? s0 : (w == 1) ? s1 : (w == 2) ? s2 : (w == 3) ? s3 : s4;
  const long off = (long)w << 20;
  const int i = blockIdx.x * 256 + threadIdx.x;
  const float4 v = *(const float4*)(src + ((long)i << 2));
  u16x4 o = { f2bf(v.x), f2bf(v.y), f2bf(v.z), f2bf(v.w) };
  *(u16x4*)(dst + off + ((long)i << 2)) = o;
}

// ---------------------------------------------------------------------------
// Memory plan (green since round 2):
//   d_out: [q|k] bf16 -> attb -> final fp32
//   ws R0 (64MiB): [xb|vb] -> S -> [hb|ff1];  R1 (32MiB): vt -> ff2;  R2: weights
// ---------------------------------------------------------------------------
extern "C" void kernel_launch(void* const* d_in, const int* in_sizes, int n_in,
                              void* d_out, int out_size, void* d_ws, size_t ws_size,
                              hipStream_t stream) {
  const int T = 2048, D = 1024;
  const long TD = (long)T * D;
  const long ND = 8 * TD;
  const float* x    = (const float*)d_in[0];
  const float* sit  = (const float*)d_in[1];
  const float* Wq   = (const float*)d_in[2];
  const float* Wk   = (const float*)d_in[3];
  const float* Wv   = (const float*)d_in[4];
  const float* ln1g = (const float*)d_in[5];
  const float* ln1b = (const float*)d_in[6];
  const float* Wf1  = (const float*)d_in[7];
  const float* bf1  = (const float*)d_in[8];
  const float* Wf2  = (const float*)d_in[9];
  const float* bf2  = (const float*)d_in[10];
  const float* ln2g = (const float*)d_in[11];
  const float* ln2b = (const float*)d_in[12];

  ushort_t* W16 = (ushort_t*)d_ws;
  ushort_t* xb  = W16;
  ushort_t* vb  = W16 + ND;
  ushort_t* S   = W16;
  ushort_t* hb  = W16;
  ushort_t* ff1 = W16 + ND;
  ushort_t* vt  = W16 + 2 * ND;
  ushort_t* ff2 = vt;
  ushort_t* wq  = W16 + 3 * ND;      // wq|wk|wv contiguous = fused [3072][1024]
  ushort_t* wf1 = wq + 3L * D * D;
  ushort_t* wf2 = wf1 + (long)D * D;
  ushort_t* qb = (ushort_t*)d_out;
  ushort_t* kb = qb + ND;
  ushort_t* attb = (ushort_t*)d_out;

  cast_f32_bf16<<<16384, 256, 0, stream>>>(x, xb, (int)(ND / 4));
  cast_w5<<<dim3(1024, 5), 256, 0, stream>>>(Wq, Wk, Wv, Wf1, Wf2, wq);

  // fused QKV: [16384,1024] @ [3072,1024]^T, epilogue routes to qb/kb/vb
  gemm256<0, 2, true><<<dim3(768), 256, 0, stream>>>(
      xb, 1024, wq, 1024, qb, kb, vb, 1024, nullptr, 1.f, 1024);

  transpose_bf16<<<dim3(16, 32, 8), 256, 0, stream>>>(vb, 1024, TD, vt, 2048, TD);

  // scores: S = Q K^T / 32, batch->XCD pinned triangular 256x128 tiles
  gemmA<0, 1, false><<<dim3(576), 512, 0, stream>>>(
      qb, 1024, TD, kb, 1024, TD, S, 2048, (long)T * T, nullptr, 0.03125f, 1024);

  softmax_sit2<<<8192, 256, 0, stream>>>(S, sit);

  // att = P @ V, batch->XCD pinned heavy-first tiles, K=(by+1)*256
  gemmA<0, 2, true><<<dim3(512), 512, 0, stream>>>(
      S, 2048, (long)T * T, vt, 2048, TD, attb, 1024, TD, nullptr, 1.f, 2048);

  resid_ln<true, false><<<16384, 256, 0, stream>>>(attb, x, ln1g, ln1b, hb);

  gemm256<2, 1, false><<<dim3(4, 64), 256, 0, stream>>>(
      hb, 1024, wf1, 1024, ff1, ff1, ff1, 1024, bf1, 1.f, 1024);
  gemm256<1, 1, false><<<dim3(4, 64), 256, 0, stream>>>(
      ff1, 1024, wf2, 1024, ff2, ff2, ff2, 1024, bf2, 1.f, 1024);

  resid_ln<false, true><<<16384, 256, 0, stream>>>(ff2, hb, ln2g, ln2b, (float*)d_out);
}

// Round 13
// 391.862 us; speedup vs baseline: 1.5189x; 1.5189x over previous
//
#include <hip/hip_runtime.h>

typedef unsigned short ushort_t;
typedef __attribute__((ext_vector_type(8))) __bf16 bf16x8;
typedef __attribute__((ext_vector_type(4))) float f32x4;
typedef __attribute__((ext_vector_type(4))) int i32x4;
typedef __attribute__((ext_vector_type(4))) unsigned short u16x4;
typedef __attribute__((ext_vector_type(8))) unsigned short u16x8;

__device__ __forceinline__ float bf2f(ushort_t u) {
  union { unsigned u32; float f; } c; c.u32 = ((unsigned)u) << 16; return c.f;
}
__device__ __forceinline__ ushort_t f2bf(float f) {
  union { float f; unsigned u32; } c; c.f = f;
  unsigned u = c.u32;
  u += 0x7fffu + ((u >> 16) & 1u);
  return (ushort_t)(u >> 16);
}

__device__ __forceinline__ void gload_lds16(const void* g, void* l) {
  __builtin_amdgcn_global_load_lds(
      (const __attribute__((address_space(1))) void*)g,
      (__attribute__((address_space(3))) void*)l,
      16, 0, 0);
}

// 512-thread stager: one 128x64 bf16 half-tile (2 gloads/thread)
__device__ __forceinline__ void stage_half(const char* gbase, long row0, int ldbytes,
                                           int kbyte, char* lds_half, int tid)
{
  const int rl = tid >> 3;
  const int cs = ((tid & 7) ^ (rl & 7)) << 4;
  const char* g0 = gbase + (row0 + rl) * (long)ldbytes + kbyte + cs;
  char* l0 = lds_half + ((tid >> 6) << 10);
  gload_lds16(g0, l0);
  gload_lds16(g0 + (long)ldbytes * 64, l0 + 8192);
}

#define BAR() __builtin_amdgcn_s_barrier()
#define VMW6() asm volatile("s_waitcnt vmcnt(6)" ::: "memory")
#define VMW8() asm volatile("s_waitcnt vmcnt(8)" ::: "memory")
#define LGKM0() asm volatile("s_waitcnt lgkmcnt(0)" ::: "memory")
#define PR1() __builtin_amdgcn_s_setprio(1)
#define PR0() __builtin_amdgcn_s_setprio(0)

// 16x16x32 fragment reads (conflict-free: per-16-lane group XOR key g)
#define RD_A4(dst, base, rb) \
  _Pragma("unroll") for (int m_ = 0; m_ < 4; ++m_) { \
    const char* p_ = (base) + ((rb) + m_ * 16 + fr) * 128; \
    dst[m_][0] = *(const bf16x8*)(p_ + ch0); \
    dst[m_][1] = *(const bf16x8*)(p_ + ch1); }
#define RD_B2(dst, base, cb) \
  _Pragma("unroll") for (int n_ = 0; n_ < 2; ++n_) { \
    const char* p_ = (base) + ((cb) + n_ * 16 + fr) * 128; \
    dst[n_][0] = *(const bf16x8*)(p_ + ch0); \
    dst[n_][1] = *(const bf16x8*)(p_ + ch1); }

// ===========================================================================
// gemm256: 256x256 bf16 NT GEMM. Region-pipelined schedule (round-11 proven):
// 4 barriers per 2 K-tiles; lgkm0+BAR before buffer overwrite; counted
// vmcnt(8)+BAR publish. 8 waves (2Mx4N), wave 128x64, VGPR 116, 0 conflicts.
// MAPQ=2 (fused QKV): per XCD all 8 A-panels persist in L2 (by=(u&7)*8+c),
// B-panels stream 4 per round (bx=u>>3).
// ===========================================================================
#define G_MM(ib, jb, Aa, Bb) \
  _Pragma("unroll") for (int m_ = 0; m_ < 4; ++m_) \
  _Pragma("unroll") for (int n_ = 0; n_ < 2; ++n_) \
  _Pragma("unroll") for (int s_ = 0; s_ < 2; ++s_) \
    acc[(ib) + m_][(jb) + n_] = __builtin_amdgcn_mfma_f32_16x16x32_bf16( \
        Aa[m_][s_], Bb[n_][s_], acc[(ib) + m_][(jb) + n_], 0, 0, 0);
#define SAE_(t, hh) stage_half(gA, m0 + (hh) * 128, ldab, (t) << 7, AE + (hh) * 16384, tid)
#define SAO_(t, hh) stage_half(gA, m0 + (hh) * 128, ldab, (t) << 7, AO + (hh) * 16384, tid)
#define SBE_(t, hh) stage_half(gB, n0 + (hh) * 128, ldbb, (t) << 7, BE + (hh) * 16384, tid)
#define SBO_(t, hh) stage_half(gB, n0 + (hh) * 128, ldbb, (t) << 7, BO + (hh) * 16384, tid)

template<int EPI, int MAPQ, bool ROUTE>
__global__ __launch_bounds__(512, 1) void gemm256(
    const ushort_t* __restrict__ A, int lda,
    const ushort_t* __restrict__ B, int ldb,
    ushort_t* __restrict__ C0, ushort_t* __restrict__ C1, ushort_t* __restrict__ C2,
    int ldc, const float* __restrict__ bias, float scale, int K)
{
  __shared__ __attribute__((aligned(16))) ushort_t lds[65536];

  int bx, by;
  if (MAPQ == 1) {
    const int flat = blockIdx.y * 4 + blockIdx.x;       // grid 4x64
    by = ((flat >> 5) << 3) | (flat & 7);
    bx = (flat >> 3) & 3;
  } else if (MAPQ == 2) {                               // fused QKV grid 768
    const int l = blockIdx.x;
    const int c = l & 7, u = l >> 3;                    // c=XCD, u=0..95
    by = ((u & 7) << 3) | c;                            // 8 persistent A-panels/XCD
    bx = u >> 3;                                        // 0..11, 4 B-panels/round
  } else { bx = blockIdx.x; by = blockIdx.y; }

  const int NT = K >> 6, NIT = NT >> 1, NTm1 = NT - 1;

  const int tid = threadIdx.x, lane = tid & 63;
  const int fr = lane & 15, g = lane >> 4, lm = lane & 7;
  const int wv = tid >> 6, wr = wv >> 2, wc = wv & 3;
  const int wrb = wr << 7, wcb = wc << 6;
  const long m0 = (long)by << 8, n0 = (long)bx << 8;

  const char* gA = (const char*)A;
  const char* gB = (const char*)B;
  const int ldab = lda << 1, ldbb = ldb << 1;

  const int ch0 = (g ^ lm) << 4;
  const int ch1 = ((4 | g) ^ lm) << 4;

  char* AE = (char*)lds;
  char* AO = AE + 32768;
  char* BE = AE + 65536;
  char* BO = AE + 98304;

  f32x4 acc[8][4] = {};
  bf16x8 aF[4][2], aG[4][2], bL[2][2], bL2[2][2], bH[2][2];

  // prologue: stage T0 (8 loads) + T1 (8 loads); vmcnt(8) -> T0 landed
  SAE_(0, 0); SAE_(0, 1); SBE_(0, 0); SBE_(0, 1);
  SAO_(1, 0); SAO_(1, 1); SBO_(1, 0); SBO_(1, 1);
  VMW8(); BAR();
  RD_A4(aF, AE, wrb); RD_B2(bL, BE, wcb);

  for (int i = 0; i < NIT; ++i) {
    const int t2 = (2 * i + 2 < NTm1) ? 2 * i + 2 : NTm1;
    const int t3 = (2 * i + 3 < NTm1) ? 2 * i + 3 : NTm1;

    // region A: e quadrants (mlo,nlo)+(mlo,nhi); reads flow with MFMA
    PR1(); G_MM(0, 0, aF, bL); PR0();
    RD_B2(bH, BE, wcb + 32);
    PR1(); G_MM(0, 2, aF, bH); PR0();
    RD_A4(aG, AE, wrb + 64);
    LGKM0(); BAR();                       // all bufE reads complete everywhere
    // region B: e quadrants (mhi,nhi)+(mhi,nlo); stage bufE<-t2 (now safe)
    PR1(); G_MM(4, 2, aG, bH); PR0();
    SAE_(t2, 0); SAE_(t2, 1); SBE_(t2, 0); SBE_(t2, 1);
    PR1(); G_MM(4, 0, aG, bL); PR0();
    VMW8(); BAR();                        // drains bufO stages -> publish
    RD_A4(aF, AO, wrb); RD_B2(bL2, BO, wcb);
    // region C: o quadrants 1+2
    PR1(); G_MM(0, 0, aF, bL2); PR0();
    RD_B2(bH, BO, wcb + 32);
    PR1(); G_MM(0, 2, aF, bH); PR0();
    RD_A4(aG, AO, wrb + 64);
    LGKM0(); BAR();                       // all bufO reads complete
    // region D: o quadrants 3+4; stage bufO<-t3
    PR1(); G_MM(4, 2, aG, bH); PR0();
    SAO_(t3, 0); SAO_(t3, 1); SBO_(t3, 0); SBO_(t3, 1);
    PR1(); G_MM(4, 0, aG, bL2); PR0();
    VMW8(); BAR();                        // drains bufE(t2) -> publish
    RD_A4(aF, AE, wrb); RD_B2(bL, BE, wcb);
  }

  ushort_t* Cd = C0;
  long nc0 = (long)bx << 8;
  if constexpr (ROUTE) {
    const int which = bx >> 2;
    Cd = (which == 0) ? C0 : (which == 1) ? C1 : C2;
    nc0 = (long)(bx & 3) << 8;
  }

  const int cm = g << 2, cn = fr;
#pragma unroll
  for (int i2 = 0; i2 < 8; ++i2)
#pragma unroll
    for (int j2 = 0; j2 < 4; ++j2) {
      const long gm = m0 + wrb + i2 * 16 + cm;
      const long gn = nc0 + wcb + j2 * 16 + cn;
      float bv = 0.f;
      if constexpr (EPI >= 1) bv = bias[gn];
#pragma unroll
      for (int r = 0; r < 4; ++r) {
        float v = acc[i2][j2][r] * scale + bv;
        if constexpr (EPI == 2) v = fmaxf(v, 0.f);
        Cd[(gm + r) * ldc + gn] = f2bf(v);
      }
    }
}

// ===========================================================================
// gemmA: 256x128 bf16 NT GEMM, region-pipelined: 2 barriers per 2 K-tiles.
// Triple-buffered LDS (144 KiB); counted vmcnt(6) FIFO (round-11 proven).
// MAP: 1 = triangular scores (576 blocks, bz=bid&7),
//      2 = PV balanced-pair map: by=perm[u>>3], perm={7,6,5,4,0,1,2,3} so
//          CU pairs (8,1),(7,2),(6,3),(5,4) all sum K=9*256 (was 12 vs 6).
// ===========================================================================
#define A_MM(jb, Aa, Bb) \
  _Pragma("unroll") for (int m_ = 0; m_ < 4; ++m_) \
  _Pragma("unroll") for (int n_ = 0; n_ < 2; ++n_) \
  _Pragma("unroll") for (int s_ = 0; s_ < 2; ++s_) \
    acc[m_][(jb) + n_] = __builtin_amdgcn_mfma_f32_16x16x32_bf16( \
        Aa[m_][s_], Bb[n_][s_], acc[m_][(jb) + n_], 0, 0, 0);
#define SAA_(t, hh, dst) stage_half(gA, m0 + (hh) * 128, ldab, (t) << 7, (dst) + (hh) * 16384, tid)
#define SBA_(t, dst) stage_half(gB, n0, ldbb, (t) << 7, (dst), tid)

template<int EPI, int MAP, bool CKLIM>
__global__ __launch_bounds__(512, 1) void gemmA(
    const ushort_t* __restrict__ A, int lda, long bsA,
    const ushort_t* __restrict__ B, int ldb, long bsB,
    ushort_t* __restrict__ C, int ldc, long bsC,
    const float* __restrict__ bias, float scale, int K)
{
  __shared__ __attribute__((aligned(16))) ushort_t lds[73728];  // 144 KiB

  int bx, by, bz;
  if (MAP == 1) {
    const int bid = blockIdx.x;
    bz = bid & 7; const int r = bid >> 3;
    by = 0; while ((by + 1) * (by + 2) <= r) ++by;
    bx = r - by * (by + 1);
  } else if (MAP == 2) {
    const int bid = blockIdx.x;
    bz = bid & 7; const int u = bid >> 3;
    const int perm[8] = {7, 6, 5, 4, 0, 1, 2, 3};
    by = perm[u >> 3]; bx = u & 7;
  } else { bx = blockIdx.x; by = blockIdx.y; bz = blockIdx.z; }

  const int NT = CKLIM ? ((by + 1) << 2) : (K >> 6);
  const int NIT = NT >> 1, NTm1 = NT - 1;   // NT always even here

  const int tid = threadIdx.x, lane = tid & 63;
  const int fr = lane & 15, g = lane >> 4, lm = lane & 7;
  const int wv = tid >> 6, wr4 = wv >> 1, wc2 = wv & 1;
  const int wrb = wr4 << 6, wcb = wc2 << 6;
  const long m0 = (long)by << 8, n0 = (long)bx << 7;

  const char* gA = (const char*)(A + bz * bsA);
  const char* gB = (const char*)(B + bz * bsB);
  const int ldab = lda << 1, ldbb = ldb << 1;

  const int ch0 = (g ^ lm) << 4;
  const int ch1 = ((4 | g) ^ lm) << 4;

  // roles: pE holds tile e, pO tile o=e+1, pS spare (receives tile e+2)
  char* pEA = (char*)lds;          char* pEB = pEA + 32768;
  char* pOA = (char*)lds + 49152;  char* pOB = pOA + 32768;
  char* pSA = (char*)lds + 98304;  char* pSB = pSA + 32768;

  f32x4 acc[4][4] = {};
  bf16x8 aE[4][2], aO[4][2], bLE[2][2], bLO[2][2], bH[2][2];

  // prologue: stage T0 (6), T1 (6); vmcnt(6) -> T0 landed; read e-frags
  SAA_(0, 0, pEA); SAA_(0, 1, pEA); SBA_(0, pEB);
  SAA_(1, 0, pOA); SAA_(1, 1, pOA); SBA_(1, pOB);
  VMW6(); BAR();
  RD_A4(aE, pEA, wrb); RD_B2(bLE, pEB, wcb);

  for (int i = 0; i < NIT; ++i) {
    const int t2 = (2 * i + 2 < NTm1) ? 2 * i + 2 : NTm1;
    const int t3 = (2 * i + 3 < NTm1) ? 2 * i + 3 : NTm1;

    // region A: tile e; stage t2 -> spare (dead buffer, no hazard)
    PR1(); A_MM(0, aE, bLE); PR0();
    RD_B2(bH, pEB, wcb + 32);
    SAA_(t2, 0, pSA); SAA_(t2, 1, pSA); SBA_(t2, pSB);
    PR1(); A_MM(2, aE, bH); PR0();
    LGKM0(); VMW6(); BAR();               // lgkm: pE reads done; vmcnt drains tile o
    // region B: tile o; stage t3 -> pE (protected by barrier above)
    RD_A4(aO, pOA, wrb); RD_B2(bLO, pOB, wcb);
    PR1(); A_MM(0, aO, bLO); PR0();
    RD_B2(bH, pOB, wcb + 32);
    SAA_(t3, 0, pEA); SAA_(t3, 1, pEA); SBA_(t3, pEB);
    PR1(); A_MM(2, aO, bH); PR0();
    LGKM0(); VMW6(); BAR();               // lgkm: pO reads done; vmcnt drains t2
    RD_A4(aE, pSA, wrb); RD_B2(bLE, pSB, wcb);
    // rotate roles: (E,O,S) <- (S,E,O)
    char* tA = pEA; pEA = pSA; pSA = pOA; pOA = tA;
    char* tB = pEB; pEB = pSB; pSB = pOB; pOB = tB;
  }

  ushort_t* Cb = C + bz * bsC;
  const int cm = g << 2, cn = fr;
#pragma unroll
  for (int i2 = 0; i2 < 4; ++i2)
#pragma unroll
    for (int j2 = 0; j2 < 4; ++j2) {
      const long gm = m0 + wrb + i2 * 16 + cm;
      const long gn = n0 + wcb + j2 * 16 + cn;
      float bv = 0.f;
      if constexpr (EPI >= 1) bv = bias[gn];
#pragma unroll
      for (int r = 0; r < 4; ++r) {
        float v = acc[i2][j2][r] * scale + bv;
        if constexpr (EPI == 2) v = fmaxf(v, 0.f);
        Cb[(gm + r) * ldc + gn] = f2bf(v);
      }
    }
}

// ---------------------------------------------------------------------------
// 64x64 bf16 transpose: Vt[d][s] = V[s][d]
// ---------------------------------------------------------------------------
__global__ __launch_bounds__(256) void transpose_bf16(
    const ushort_t* __restrict__ V, int ldv, long bsV,
    ushort_t* __restrict__ Vt, int ldt, long bsT)
{
  __shared__ __attribute__((aligned(16))) ushort_t tile[64][72];
  const int bz = blockIdx.z;
  const ushort_t* Vb = V + bz * bsV;
  ushort_t* Tb = Vt + bz * bsT;
  const long s0 = (long)blockIdx.y << 6;
  const long d0 = (long)blockIdx.x << 6;
  const int tid = threadIdx.x;
  const int r = tid >> 3, c = tid & 7;
#pragma unroll
  for (int hh = 0; hh < 2; ++hh) {
    const int rr = r + hh * 32;
    i32x4 v = *(const i32x4*)(Vb + (s0 + rr) * ldv + d0 + c * 8);
    *(i32x4*)&tile[rr][c * 8] = v;
  }
  __syncthreads();
#pragma unroll
  for (int hh = 0; hh < 2; ++hh) {
    const int dr = r + hh * 32;
    union { ushort_t u[8]; i32x4 v; } t;
#pragma unroll
    for (int j = 0; j < 8; ++j) t.u[j] = tile[c * 8 + j][dr];
    *(i32x4*)(Tb + (d0 + dr) * ldt + s0 + c * 8) = t.v;
  }
}

// ---------------------------------------------------------------------------
// Row softmax, register-resident, TWO complementary rows per block.
// ---------------------------------------------------------------------------
__global__ __launch_bounds__(256) void softmax_sit2(ushort_t* __restrict__ S,
                                                    const float* __restrict__ sit)
{
  __shared__ float redA[4], redB[4];
  const int bid = blockIdx.x;               // 0..8191
  const long rowA = bid, rowB = 16383 - bid;
  const int bA = (int)(rowA >> 11), tA = (int)(rowA & 2047);
  const int bB = (int)(rowB >> 11), tB = (int)(rowB & 2047);
  const int nA = tA + 1, nB = tB + 1;
  const int rupA = ((tA >> 8) + 1) << 8, rupB = ((tB >> 8) + 1) << 8;
  ushort_t* SrA = S + (rowA << 11);
  ushort_t* SrB = S + (rowB << 11);
  const int tid = threadIdx.x;
  const int i0 = tid << 3;
  const bool actA = i0 < rupA, actB = i0 < rupB;

  u16x8 rawA = {}, rawB = {};
  if (actA) rawA = *(const u16x8*)(SrA + i0);
  if (actB) rawB = *(const u16x8*)(SrB + i0);
  float vA[8], vB[8];
#pragma unroll
  for (int j = 0; j < 8; ++j) { vA[j] = bf2f(rawA[j]); vB[j] = bf2f(rawB[j]); }

  float mA = -3.0e38f, mB = -3.0e38f;
#pragma unroll
  for (int j = 0; j < 8; ++j) {
    if (i0 + j < nA) mA = fmaxf(mA, vA[j]);
    if (i0 + j < nB) mB = fmaxf(mB, vB[j]);
  }
#pragma unroll
  for (int o = 32; o > 0; o >>= 1) {
    mA = fmaxf(mA, __shfl_down(mA, o, 64));
    mB = fmaxf(mB, __shfl_down(mB, o, 64));
  }
  if ((tid & 63) == 0) { redA[tid >> 6] = mA; redB[tid >> 6] = mB; }
  __syncthreads();
  const float mxA = fmaxf(fmaxf(redA[0], redA[1]), fmaxf(redA[2], redA[3]));
  const float mxB = fmaxf(fmaxf(redB[0], redB[1]), fmaxf(redB[2], redB[3]));
  __syncthreads();

  float eA[8], eB[8];
  float sA = 0.f, sB = 0.f;
#pragma unroll
  for (int j = 0; j < 8; ++j) {
    eA[j] = (i0 + j < nA) ? __expf(vA[j] - mxA) : 0.f;
    eB[j] = (i0 + j < nB) ? __expf(vB[j] - mxB) : 0.f;
    sA += eA[j]; sB += eB[j];
  }
#pragma unroll
  for (int o = 32; o > 0; o >>= 1) {
    sA += __shfl_down(sA, o, 64);
    sB += __shfl_down(sB, o, 64);
  }
  if ((tid & 63) == 0) { redA[tid >> 6] = sA; redB[tid >> 6] = sB; }
  __syncthreads();
  const float lA = redA[0] + redA[1] + redA[2] + redA[3];
  const float lB = redB[0] + redB[1] + redB[2] + redB[3];

  float invA = 1.f / lA, invB = 1.f / lB;
  if (sit[rowA] == 0.f) invA = 0.f;
  if (sit[rowB] == 0.f) invB = 0.f;
  if (actA) {
    const float* sb = sit + ((long)bA << 11) + i0;
    u16x8 out;
#pragma unroll
    for (int j = 0; j < 8; ++j)
      out[j] = f2bf((i0 + j < nA && sb[j] != 0.f) ? eA[j] * invA : 0.f);
    *(u16x8*)(SrA + i0) = out;
  }
  if (actB) {
    const float* sb = sit + ((long)bB << 11) + i0;
    u16x8 out;
#pragma unroll
    for (int j = 0; j < 8; ++j)
      out[j] = f2bf((i0 + j < nB && sb[j] != 0.f) ? eB[j] * invB : 0.f);
    *(u16x8*)(SrB + i0) = out;
  }
}

// ---------------------------------------------------------------------------
// out = LN(xin + res) * g + b ; D = 1024, one block per row
// ---------------------------------------------------------------------------
template<bool RES_F32, bool OUT_F32>
__global__ __launch_bounds__(256) void resid_ln(
    const ushort_t* __restrict__ xin, const void* __restrict__ resv,
    const float* __restrict__ g, const float* __restrict__ be, void* __restrict__ outv)
{
  __shared__ float red[4];
  const long base = (long)blockIdx.x << 10;
  const int tid = threadIdx.x;
  const int i0 = tid << 2;

  const u16x4 xa = *(const u16x4*)(xin + base + i0);
  float v[4];
  if constexpr (RES_F32) {
    const float4 rv = *(const float4*)((const float*)resv + base + i0);
    v[0] = bf2f(xa.x) + rv.x; v[1] = bf2f(xa.y) + rv.y;
    v[2] = bf2f(xa.z) + rv.z; v[3] = bf2f(xa.w) + rv.w;
  } else {
    const u16x4 rb = *(const u16x4*)((const ushort_t*)resv + base + i0);
    v[0] = bf2f(xa.x) + bf2f(rb.x); v[1] = bf2f(xa.y) + bf2f(rb.y);
    v[2] = bf2f(xa.z) + bf2f(rb.z); v[3] = bf2f(xa.w) + bf2f(rb.w);
  }
  float s = v[0] + v[1] + v[2] + v[3];
#pragma unroll
  for (int o = 32; o > 0; o >>= 1) s += __shfl_down(s, o, 64);
  if ((tid & 63) == 0) red[tid >> 6] = s;
  __syncthreads();
  const float mu = (red[0] + red[1] + red[2] + red[3]) * (1.f / 1024.f);
  __syncthreads();
  float s2 = 0.f;
#pragma unroll
  for (int j = 0; j < 4; ++j) { const float d = v[j] - mu; s2 += d * d; }
#pragma unroll
  for (int o = 32; o > 0; o >>= 1) s2 += __shfl_down(s2, o, 64);
  if ((tid & 63) == 0) red[tid >> 6] = s2;
  __syncthreads();
  const float rstd = rsqrtf((red[0] + red[1] + red[2] + red[3]) * (1.f / 1024.f) + 1e-5f);

  const float4 gv = *(const float4*)(g + i0);
  const float4 bv = *(const float4*)(be + i0);
  const float o0 = (v[0] - mu) * rstd * gv.x + bv.x;
  const float o1 = (v[1] - mu) * rstd * gv.y + bv.y;
  const float o2 = (v[2] - mu) * rstd * gv.z + bv.z;
  const float o3 = (v[3] - mu) * rstd * gv.w + bv.w;
  if constexpr (OUT_F32) {
    float4 ov; ov.x = o0; ov.y = o1; ov.z = o2; ov.w = o3;
    *(float4*)((float*)outv + base + i0) = ov;
  } else {
    u16x4 ob = { f2bf(o0), f2bf(o1), f2bf(o2), f2bf(o3) };
    *(u16x4*)((ushort_t*)outv + base + i0) = ob;
  }
}

__global__ __launch_bounds__(256) void cast_f32_bf16(const float* __restrict__ src,
                                                     ushort_t* __restrict__ dst, int n4)
{
  const int i = blockIdx.x * 256 + threadIdx.x;
  if (i >= n4) return;
  const float4 v = *(const float4*)(src + ((long)i << 2));
  u16x4 o = { f2bf(v.x), f2bf(v.y), f2bf(v.z), f2bf(v.w) };
  *(u16x4*)(dst + ((long)i << 2)) = o;
}

__global__ __launch_bounds__(256) void cast_w5(
    const float* __restrict__ s0, const float* __restrict__ s1,
    const float* __restrict__ s2, const float* __restrict__ s3,
    const float* __restrict__ s4, ushort_t* __restrict__ dst)
{
  const int w = blockIdx.y;
  const float* src = (w == 0) ? s0 : (w == 1) ? s1 : (w == 2) ? s2 : (w == 3) ? s3 : s4;
  const long off = (long)w << 20;
  const int i = blockIdx.x * 256 + threadIdx.x;
  const float4 v = *(const float4*)(src + ((long)i << 2));
  u16x4 o = { f2bf(v.x), f2bf(v.y), f2bf(v.z), f2bf(v.w) };
  *(u16x4*)(dst + off + ((long)i << 2)) = o;
}

// ---------------------------------------------------------------------------
// Memory plan (green since round 2):
//   d_out: [q|k] bf16 -> attb -> final fp32
//   ws R0 (64MiB): [xb|vb] -> S -> [hb|ff1];  R1 (32MiB): vt -> ff2;  R2: weights
// ---------------------------------------------------------------------------
extern "C" void kernel_launch(void* const* d_in, const int* in_sizes, int n_in,
                              void* d_out, int out_size, void* d_ws, size_t ws_size,
                              hipStream_t stream) {
  const int T = 2048, D = 1024;
  const long TD = (long)T * D;
  const long ND = 8 * TD;
  const float* x    = (const float*)d_in[0];
  const float* sit  = (const float*)d_in[1];
  const float* Wq   = (const float*)d_in[2];
  const float* Wk   = (const float*)d_in[3];
  const float* Wv   = (const float*)d_in[4];
  const float* ln1g = (const float*)d_in[5];
  const float* ln1b = (const float*)d_in[6];
  const float* Wf1  = (const float*)d_in[7];
  const float* bf1  = (const float*)d_in[8];
  const float* Wf2  = (const float*)d_in[9];
  const float* bf2  = (const float*)d_in[10];
  const float* ln2g = (const float*)d_in[11];
  const float* ln2b = (const float*)d_in[12];

  ushort_t* W16 = (ushort_t*)d_ws;
  ushort_t* xb  = W16;
  ushort_t* vb  = W16 + ND;
  ushort_t* S   = W16;
  ushort_t* hb  = W16;
  ushort_t* ff1 = W16 + ND;
  ushort_t* vt  = W16 + 2 * ND;
  ushort_t* ff2 = vt;
  ushort_t* wq  = W16 + 3 * ND;      // wq|wk|wv contiguous = fused [3072][1024]
  ushort_t* wf1 = wq + 3L * D * D;
  ushort_t* wf2 = wf1 + (long)D * D;
  ushort_t* qb = (ushort_t*)d_out;
  ushort_t* kb = qb + ND;
  ushort_t* attb = (ushort_t*)d_out;

  cast_f32_bf16<<<16384, 256, 0, stream>>>(x, xb, (int)(ND / 4));
  cast_w5<<<dim3(1024, 5), 256, 0, stream>>>(Wq, Wk, Wv, Wf1, Wf2, wq);

  // fused QKV: [16384,1024] @ [3072,1024]^T, epilogue routes to qb/kb/vb
  gemm256<0, 2, true><<<dim3(768), 512, 0, stream>>>(
      xb, 1024, wq, 1024, qb, kb, vb, 1024, nullptr, 1.f, 1024);

  transpose_bf16<<<dim3(16, 32, 8), 256, 0, stream>>>(vb, 1024, TD, vt, 2048, TD);

  // scores: S = Q K^T / 32, batch->XCD pinned triangular 256x128 tiles
  gemmA<0, 1, false><<<dim3(576), 512, 0, stream>>>(
      qb, 1024, TD, kb, 1024, TD, S, 2048, (long)T * T, nullptr, 0.03125f, 1024);

  softmax_sit2<<<8192, 256, 0, stream>>>(S, sit);

  // att = P @ V, batch->XCD pinned balanced-pair tiles, K=(by+1)*256
  gemmA<0, 2, true><<<dim3(512), 512, 0, stream>>>(
      S, 2048, (long)T * T, vt, 2048, TD, attb, 1024, TD, nullptr, 1.f, 2048);

  resid_ln<true, false><<<16384, 256, 0, stream>>>(attb, x, ln1g, ln1b, hb);

  gemm256<2, 1, false><<<dim3(4, 64), 512, 0, stream>>>(
      hb, 1024, wf1, 1024, ff1, ff1, ff1, 1024, bf1, 1.f, 1024);
  gemm256<1, 1, false><<<dim3(4, 64), 512, 0, stream>>>(
      ff1, 1024, wf2, 1024, ff2, ff2, ff2, 1024, bf2, 1.f, 1024);

  resid_ln<false, true><<<16384, 256, 0, stream>>>(ff2, hb, ln2g, ln2b, (float*)d_out);
}

// Round 14
// 391.080 us; speedup vs baseline: 1.5220x; 1.0020x over previous
//
#include <hip/hip_runtime.h>

typedef unsigned short ushort_t;
typedef __attribute__((ext_vector_type(8))) __bf16 bf16x8;
typedef __attribute__((ext_vector_type(4))) float f32x4;
typedef __attribute__((ext_vector_type(4))) int i32x4;
typedef __attribute__((ext_vector_type(4))) unsigned short u16x4;
typedef __attribute__((ext_vector_type(8))) unsigned short u16x8;

__device__ __forceinline__ float bf2f(ushort_t u) {
  union { unsigned u32; float f; } c; c.u32 = ((unsigned)u) << 16; return c.f;
}
__device__ __forceinline__ ushort_t f2bf(float f) {
  union { float f; unsigned u32; } c; c.f = f;
  unsigned u = c.u32;
  u += 0x7fffu + ((u >> 16) & 1u);
  return (ushort_t)(u >> 16);
}

__device__ __forceinline__ void gload_lds16(const void* g, void* l) {
  __builtin_amdgcn_global_load_lds(
      (const __attribute__((address_space(1))) void*)g,
      (__attribute__((address_space(3))) void*)l,
      16, 0, 0);
}

// 512-thread stager: one 128x64 bf16 half-tile (2 gloads/thread)
__device__ __forceinline__ void stage_half(const char* gbase, long row0, int ldbytes,
                                           int kbyte, char* lds_half, int tid)
{
  const int rl = tid >> 3;
  const int cs = ((tid & 7) ^ (rl & 7)) << 4;
  const char* g0 = gbase + (row0 + rl) * (long)ldbytes + kbyte + cs;
  char* l0 = lds_half + ((tid >> 6) << 10);
  gload_lds16(g0, l0);
  gload_lds16(g0 + (long)ldbytes * 64, l0 + 8192);
}

#define BAR() __builtin_amdgcn_s_barrier()
#define VMW6() asm volatile("s_waitcnt vmcnt(6)" ::: "memory")
#define VMW8() asm volatile("s_waitcnt vmcnt(8)" ::: "memory")
#define LGKM0() asm volatile("s_waitcnt lgkmcnt(0)" ::: "memory")
#define PR1() __builtin_amdgcn_s_setprio(1)
#define PR0() __builtin_amdgcn_s_setprio(0)

// 16x16x32 fragment reads (conflict-free: per-16-lane group XOR key g)
#define RD_A4(dst, base, rb) \
  _Pragma("unroll") for (int m_ = 0; m_ < 4; ++m_) { \
    const char* p_ = (base) + ((rb) + m_ * 16 + fr) * 128; \
    dst[m_][0] = *(const bf16x8*)(p_ + ch0); \
    dst[m_][1] = *(const bf16x8*)(p_ + ch1); }
#define RD_B2(dst, base, cb) \
  _Pragma("unroll") for (int n_ = 0; n_ < 2; ++n_) { \
    const char* p_ = (base) + ((cb) + n_ * 16 + fr) * 128; \
    dst[n_][0] = *(const bf16x8*)(p_ + ch0); \
    dst[n_][1] = *(const bf16x8*)(p_ + ch1); }

// ===========================================================================
// gemm256: 256x256 bf16 NT GEMM. Region-pipelined (round-11 proven): 4
// barriers per 2 K-tiles; lgkm0+BAR before overwrite; counted vmcnt(8)+BAR.
// 8 waves (2Mx4N), wave 128x64, VGPR 116, 0 bank conflicts.
// MAPQ=1 (FFN, grid 4x64): persistent-A XCD map -- 8 A-panels/XCD, each x4.
// MAPQ=2 (fused QKV, grid 768): 8 A-panels persist/XCD across 12 B-rounds.
// ===========================================================================
#define G_MM(ib, jb, Aa, Bb) \
  _Pragma("unroll") for (int m_ = 0; m_ < 4; ++m_) \
  _Pragma("unroll") for (int n_ = 0; n_ < 2; ++n_) \
  _Pragma("unroll") for (int s_ = 0; s_ < 2; ++s_) \
    acc[(ib) + m_][(jb) + n_] = __builtin_amdgcn_mfma_f32_16x16x32_bf16( \
        Aa[m_][s_], Bb[n_][s_], acc[(ib) + m_][(jb) + n_], 0, 0, 0);
#define SAE_(t, hh) stage_half(gA, m0 + (hh) * 128, ldab, (t) << 7, AE + (hh) * 16384, tid)
#define SAO_(t, hh) stage_half(gA, m0 + (hh) * 128, ldab, (t) << 7, AO + (hh) * 16384, tid)
#define SBE_(t, hh) stage_half(gB, n0 + (hh) * 128, ldbb, (t) << 7, BE + (hh) * 16384, tid)
#define SBO_(t, hh) stage_half(gB, n0 + (hh) * 128, ldbb, (t) << 7, BO + (hh) * 16384, tid)

template<int EPI, int MAPQ, bool ROUTE>
__global__ __launch_bounds__(512, 1) void gemm256(
    const ushort_t* __restrict__ A, int lda,
    const ushort_t* __restrict__ B, int ldb,
    ushort_t* __restrict__ C0, ushort_t* __restrict__ C1, ushort_t* __restrict__ C2,
    int ldc, const float* __restrict__ bias, float scale, int K)
{
  __shared__ __attribute__((aligned(16))) ushort_t lds[65536];

  int bx, by;
  if (MAPQ == 1) {                                      // FFN grid 4x64
    const int flat = blockIdx.y * 4 + blockIdx.x;
    const int c = flat & 7, u = flat >> 3;              // c=XCD, u=0..31
    by = ((u & 7) << 3) | c;                            // 8 persistent A-panels/XCD
    bx = u >> 3;                                        // 0..3
  } else if (MAPQ == 2) {                               // fused QKV grid 768
    const int l = blockIdx.x;
    const int c = l & 7, u = l >> 3;                    // c=XCD, u=0..95
    by = ((u & 7) << 3) | c;                            // 8 persistent A-panels/XCD
    bx = u >> 3;                                        // 0..11
  } else { bx = blockIdx.x; by = blockIdx.y; }

  const int NT = K >> 6, NIT = NT >> 1, NTm1 = NT - 1;

  const int tid = threadIdx.x, lane = tid & 63;
  const int fr = lane & 15, g = lane >> 4, lm = lane & 7;
  const int wv = tid >> 6, wr = wv >> 2, wc = wv & 3;
  const int wrb = wr << 7, wcb = wc << 6;
  const long m0 = (long)by << 8, n0 = (long)bx << 8;

  const char* gA = (const char*)A;
  const char* gB = (const char*)B;
  const int ldab = lda << 1, ldbb = ldb << 1;

  const int ch0 = (g ^ lm) << 4;
  const int ch1 = ((4 | g) ^ lm) << 4;

  char* AE = (char*)lds;
  char* AO = AE + 32768;
  char* BE = AE + 65536;
  char* BO = AE + 98304;

  f32x4 acc[8][4] = {};
  bf16x8 aF[4][2], aG[4][2], bL[2][2], bL2[2][2], bH[2][2];

  // prologue: stage T0 (8 loads) + T1 (8 loads); vmcnt(8) -> T0 landed
  SAE_(0, 0); SAE_(0, 1); SBE_(0, 0); SBE_(0, 1);
  SAO_(1, 0); SAO_(1, 1); SBO_(1, 0); SBO_(1, 1);
  VMW8(); BAR();
  RD_A4(aF, AE, wrb); RD_B2(bL, BE, wcb);

  for (int i = 0; i < NIT; ++i) {
    const int t2 = (2 * i + 2 < NTm1) ? 2 * i + 2 : NTm1;
    const int t3 = (2 * i + 3 < NTm1) ? 2 * i + 3 : NTm1;

    // region A: e quadrants (mlo,nlo)+(mlo,nhi); reads flow with MFMA
    PR1(); G_MM(0, 0, aF, bL); PR0();
    RD_B2(bH, BE, wcb + 32);
    PR1(); G_MM(0, 2, aF, bH); PR0();
    RD_A4(aG, AE, wrb + 64);
    LGKM0(); BAR();                       // all bufE reads complete everywhere
    // region B: e quadrants (mhi,nhi)+(mhi,nlo); stage bufE<-t2 (now safe)
    PR1(); G_MM(4, 2, aG, bH); PR0();
    SAE_(t2, 0); SAE_(t2, 1); SBE_(t2, 0); SBE_(t2, 1);
    PR1(); G_MM(4, 0, aG, bL); PR0();
    VMW8(); BAR();                        // drains bufO stages -> publish
    RD_A4(aF, AO, wrb); RD_B2(bL2, BO, wcb);
    // region C: o quadrants 1+2
    PR1(); G_MM(0, 0, aF, bL2); PR0();
    RD_B2(bH, BO, wcb + 32);
    PR1(); G_MM(0, 2, aF, bH); PR0();
    RD_A4(aG, AO, wrb + 64);
    LGKM0(); BAR();                       // all bufO reads complete
    // region D: o quadrants 3+4; stage bufO<-t3
    PR1(); G_MM(4, 2, aG, bH); PR0();
    SAO_(t3, 0); SAO_(t3, 1); SBO_(t3, 0); SBO_(t3, 1);
    PR1(); G_MM(4, 0, aG, bL2); PR0();
    VMW8(); BAR();                        // drains bufE(t2) -> publish
    RD_A4(aF, AE, wrb); RD_B2(bL, BE, wcb);
  }

  ushort_t* Cd = C0;
  long nc0 = (long)bx << 8;
  if constexpr (ROUTE) {
    const int which = bx >> 2;
    Cd = (which == 0) ? C0 : (which == 1) ? C1 : C2;
    nc0 = (long)(bx & 3) << 8;
  }

  const int cm = g << 2, cn = fr;
#pragma unroll
  for (int i2 = 0; i2 < 8; ++i2)
#pragma unroll
    for (int j2 = 0; j2 < 4; ++j2) {
      const long gm = m0 + wrb + i2 * 16 + cm;
      const long gn = nc0 + wcb + j2 * 16 + cn;
      float bv = 0.f;
      if constexpr (EPI >= 1) bv = bias[gn];
#pragma unroll
      for (int r = 0; r < 4; ++r) {
        float v = acc[i2][j2][r] * scale + bv;
        if constexpr (EPI == 2) v = fmaxf(v, 0.f);
        Cd[(gm + r) * ldc + gn] = f2bf(v);
      }
    }
}

// ===========================================================================
// gemmA: 256x128 bf16 NT GEMM, region-pipelined: 2 barriers per 2 K-tiles.
// Triple-buffered LDS (144 KiB); counted vmcnt(6) FIFO (round-11 proven).
// MAP: 1 = triangular scores (576 blocks, bz=bid&7),
//      2 = PV balanced-pair map: by=perm[u>>3] so CU pairs sum K=9*256.
// ===========================================================================
#define A_MM(jb, Aa, Bb) \
  _Pragma("unroll") for (int m_ = 0; m_ < 4; ++m_) \
  _Pragma("unroll") for (int n_ = 0; n_ < 2; ++n_) \
  _Pragma("unroll") for (int s_ = 0; s_ < 2; ++s_) \
    acc[m_][(jb) + n_] = __builtin_amdgcn_mfma_f32_16x16x32_bf16( \
        Aa[m_][s_], Bb[n_][s_], acc[m_][(jb) + n_], 0, 0, 0);
#define SAA_(t, hh, dst) stage_half(gA, m0 + (hh) * 128, ldab, (t) << 7, (dst) + (hh) * 16384, tid)
#define SBA_(t, dst) stage_half(gB, n0, ldbb, (t) << 7, (dst), tid)

template<int EPI, int MAP, bool CKLIM>
__global__ __launch_bounds__(512, 1) void gemmA(
    const ushort_t* __restrict__ A, int lda, long bsA,
    const ushort_t* __restrict__ B, int ldb, long bsB,
    ushort_t* __restrict__ C, int ldc, long bsC,
    const float* __restrict__ bias, float scale, int K)
{
  __shared__ __attribute__((aligned(16))) ushort_t lds[73728];  // 144 KiB

  int bx, by, bz;
  if (MAP == 1) {
    const int bid = blockIdx.x;
    bz = bid & 7; const int r = bid >> 3;
    by = 0; while ((by + 1) * (by + 2) <= r) ++by;
    bx = r - by * (by + 1);
  } else if (MAP == 2) {
    const int bid = blockIdx.x;
    bz = bid & 7; const int u = bid >> 3;
    const int perm[8] = {7, 6, 5, 4, 0, 1, 2, 3};
    by = perm[u >> 3]; bx = u & 7;
  } else { bx = blockIdx.x; by = blockIdx.y; bz = blockIdx.z; }

  const int NT = CKLIM ? ((by + 1) << 2) : (K >> 6);
  const int NIT = NT >> 1, NTm1 = NT - 1;   // NT always even here

  const int tid = threadIdx.x, lane = tid & 63;
  const int fr = lane & 15, g = lane >> 4, lm = lane & 7;
  const int wv = tid >> 6, wr4 = wv >> 1, wc2 = wv & 1;
  const int wrb = wr4 << 6, wcb = wc2 << 6;
  const long m0 = (long)by << 8, n0 = (long)bx << 7;

  const char* gA = (const char*)(A + bz * bsA);
  const char* gB = (const char*)(B + bz * bsB);
  const int ldab = lda << 1, ldbb = ldb << 1;

  const int ch0 = (g ^ lm) << 4;
  const int ch1 = ((4 | g) ^ lm) << 4;

  // roles: pE holds tile e, pO tile o=e+1, pS spare (receives tile e+2)
  char* pEA = (char*)lds;          char* pEB = pEA + 32768;
  char* pOA = (char*)lds + 49152;  char* pOB = pOA + 32768;
  char* pSA = (char*)lds + 98304;  char* pSB = pSA + 32768;

  f32x4 acc[4][4] = {};
  bf16x8 aE[4][2], aO[4][2], bLE[2][2], bLO[2][2], bH[2][2];

  // prologue: stage T0 (6), T1 (6); vmcnt(6) -> T0 landed; read e-frags
  SAA_(0, 0, pEA); SAA_(0, 1, pEA); SBA_(0, pEB);
  SAA_(1, 0, pOA); SAA_(1, 1, pOA); SBA_(1, pOB);
  VMW6(); BAR();
  RD_A4(aE, pEA, wrb); RD_B2(bLE, pEB, wcb);

  for (int i = 0; i < NIT; ++i) {
    const int t2 = (2 * i + 2 < NTm1) ? 2 * i + 2 : NTm1;
    const int t3 = (2 * i + 3 < NTm1) ? 2 * i + 3 : NTm1;

    // region A: tile e; stage t2 -> spare (dead buffer, no hazard)
    PR1(); A_MM(0, aE, bLE); PR0();
    RD_B2(bH, pEB, wcb + 32);
    SAA_(t2, 0, pSA); SAA_(t2, 1, pSA); SBA_(t2, pSB);
    PR1(); A_MM(2, aE, bH); PR0();
    LGKM0(); VMW6(); BAR();               // lgkm: pE reads done; vmcnt drains tile o
    // region B: tile o; stage t3 -> pE (protected by barrier above)
    RD_A4(aO, pOA, wrb); RD_B2(bLO, pOB, wcb);
    PR1(); A_MM(0, aO, bLO); PR0();
    RD_B2(bH, pOB, wcb + 32);
    SAA_(t3, 0, pEA); SAA_(t3, 1, pEA); SBA_(t3, pEB);
    PR1(); A_MM(2, aO, bH); PR0();
    LGKM0(); VMW6(); BAR();               // lgkm: pO reads done; vmcnt drains t2
    RD_A4(aE, pSA, wrb); RD_B2(bLE, pSB, wcb);
    // rotate roles: (E,O,S) <- (S,E,O)
    char* tA = pEA; pEA = pSA; pSA = pOA; pOA = tA;
    char* tB = pEB; pEB = pSB; pSB = pOB; pOB = tB;
  }

  ushort_t* Cb = C + bz * bsC;
  const int cm = g << 2, cn = fr;
#pragma unroll
  for (int i2 = 0; i2 < 4; ++i2)
#pragma unroll
    for (int j2 = 0; j2 < 4; ++j2) {
      const long gm = m0 + wrb + i2 * 16 + cm;
      const long gn = n0 + wcb + j2 * 16 + cn;
      float bv = 0.f;
      if constexpr (EPI >= 1) bv = bias[gn];
#pragma unroll
      for (int r = 0; r < 4; ++r) {
        float v = acc[i2][j2][r] * scale + bv;
        if constexpr (EPI == 2) v = fmaxf(v, 0.f);
        Cb[(gm + r) * ldc + gn] = f2bf(v);
      }
    }
}

// ---------------------------------------------------------------------------
// 64x64 bf16 transpose: Vt[d][s] = V[s][d]
// ---------------------------------------------------------------------------
__global__ __launch_bounds__(256) void transpose_bf16(
    const ushort_t* __restrict__ V, int ldv, long bsV,
    ushort_t* __restrict__ Vt, int ldt, long bsT)
{
  __shared__ __attribute__((aligned(16))) ushort_t tile[64][72];
  const int bz = blockIdx.z;
  const ushort_t* Vb = V + bz * bsV;
  ushort_t* Tb = Vt + bz * bsT;
  const long s0 = (long)blockIdx.y << 6;
  const long d0 = (long)blockIdx.x << 6;
  const int tid = threadIdx.x;
  const int r = tid >> 3, c = tid & 7;
#pragma unroll
  for (int hh = 0; hh < 2; ++hh) {
    const int rr = r + hh * 32;
    i32x4 v = *(const i32x4*)(Vb + (s0 + rr) * ldv + d0 + c * 8);
    *(i32x4*)&tile[rr][c * 8] = v;
  }
  __syncthreads();
#pragma unroll
  for (int hh = 0; hh < 2; ++hh) {
    const int dr = r + hh * 32;
    union { ushort_t u[8]; i32x4 v; } t;
#pragma unroll
    for (int j = 0; j < 8; ++j) t.u[j] = tile[c * 8 + j][dr];
    *(i32x4*)(Tb + (d0 + dr) * ldt + s0 + c * 8) = t.v;
  }
}

// ---------------------------------------------------------------------------
// Row softmax, register-resident, TWO complementary rows per block.
// ---------------------------------------------------------------------------
__global__ __launch_bounds__(256) void softmax_sit2(ushort_t* __restrict__ S,
                                                    const float* __restrict__ sit)
{
  __shared__ float redA[4], redB[4];
  const int bid = blockIdx.x;               // 0..8191
  const long rowA = bid, rowB = 16383 - bid;
  const int bA = (int)(rowA >> 11), tA = (int)(rowA & 2047);
  const int bB = (int)(rowB >> 11), tB = (int)(rowB & 2047);
  const int nA = tA + 1, nB = tB + 1;
  const int rupA = ((tA >> 8) + 1) << 8, rupB = ((tB >> 8) + 1) << 8;
  ushort_t* SrA = S + (rowA << 11);
  ushort_t* SrB = S + (rowB << 11);
  const int tid = threadIdx.x;
  const int i0 = tid << 3;
  const bool actA = i0 < rupA, actB = i0 < rupB;

  u16x8 rawA = {}, rawB = {};
  if (actA) rawA = *(const u16x8*)(SrA + i0);
  if (actB) rawB = *(const u16x8*)(SrB + i0);
  float vA[8], vB[8];
#pragma unroll
  for (int j = 0; j < 8; ++j) { vA[j] = bf2f(rawA[j]); vB[j] = bf2f(rawB[j]); }

  float mA = -3.0e38f, mB = -3.0e38f;
#pragma unroll
  for (int j = 0; j < 8; ++j) {
    if (i0 + j < nA) mA = fmaxf(mA, vA[j]);
    if (i0 + j < nB) mB = fmaxf(mB, vB[j]);
  }
#pragma unroll
  for (int o = 32; o > 0; o >>= 1) {
    mA = fmaxf(mA, __shfl_down(mA, o, 64));
    mB = fmaxf(mB, __shfl_down(mB, o, 64));
  }
  if ((tid & 63) == 0) { redA[tid >> 6] = mA; redB[tid >> 6] = mB; }
  __syncthreads();
  const float mxA = fmaxf(fmaxf(redA[0], redA[1]), fmaxf(redA[2], redA[3]));
  const float mxB = fmaxf(fmaxf(redB[0], redB[1]), fmaxf(redB[2], redB[3]));
  __syncthreads();

  float eA[8], eB[8];
  float sA = 0.f, sB = 0.f;
#pragma unroll
  for (int j = 0; j < 8; ++j) {
    eA[j] = (i0 + j < nA) ? __expf(vA[j] - mxA) : 0.f;
    eB[j] = (i0 + j < nB) ? __expf(vB[j] - mxB) : 0.f;
    sA += eA[j]; sB += eB[j];
  }
#pragma unroll
  for (int o = 32; o > 0; o >>= 1) {
    sA += __shfl_down(sA, o, 64);
    sB += __shfl_down(sB, o, 64);
  }
  if ((tid & 63) == 0) { redA[tid >> 6] = sA; redB[tid >> 6] = sB; }
  __syncthreads();
  const float lA = redA[0] + redA[1] + redA[2] + redA[3];
  const float lB = redB[0] + redB[1] + redB[2] + redB[3];

  float invA = 1.f / lA, invB = 1.f / lB;
  if (sit[rowA] == 0.f) invA = 0.f;
  if (sit[rowB] == 0.f) invB = 0.f;
  if (actA) {
    const float* sb = sit + ((long)bA << 11) + i0;
    u16x8 out;
#pragma unroll
    for (int j = 0; j < 8; ++j)
      out[j] = f2bf((i0 + j < nA && sb[j] != 0.f) ? eA[j] * invA : 0.f);
    *(u16x8*)(SrA + i0) = out;
  }
  if (actB) {
    const float* sb = sit + ((long)bB << 11) + i0;
    u16x8 out;
#pragma unroll
    for (int j = 0; j < 8; ++j)
      out[j] = f2bf((i0 + j < nB && sb[j] != 0.f) ? eB[j] * invB : 0.f);
    *(u16x8*)(SrB + i0) = out;
  }
}

// ---------------------------------------------------------------------------
// out = LN(xin + res) * g + b ; D = 1024, one block per row
// ---------------------------------------------------------------------------
template<bool RES_F32, bool OUT_F32>
__global__ __launch_bounds__(256) void resid_ln(
    const ushort_t* __restrict__ xin, const void* __restrict__ resv,
    const float* __restrict__ g, const float* __restrict__ be, void* __restrict__ outv)
{
  __shared__ float red[4];
  const long base = (long)blockIdx.x << 10;
  const int tid = threadIdx.x;
  const int i0 = tid << 2;

  const u16x4 xa = *(const u16x4*)(xin + base + i0);
  float v[4];
  if constexpr (RES_F32) {
    const float4 rv = *(const float4*)((const float*)resv + base + i0);
    v[0] = bf2f(xa.x) + rv.x; v[1] = bf2f(xa.y) + rv.y;
    v[2] = bf2f(xa.z) + rv.z; v[3] = bf2f(xa.w) + rv.w;
  } else {
    const u16x4 rb = *(const u16x4*)((const ushort_t*)resv + base + i0);
    v[0] = bf2f(xa.x) + bf2f(rb.x); v[1] = bf2f(xa.y) + bf2f(rb.y);
    v[2] = bf2f(xa.z) + bf2f(rb.z); v[3] = bf2f(xa.w) + bf2f(rb.w);
  }
  float s = v[0] + v[1] + v[2] + v[3];
#pragma unroll
  for (int o = 32; o > 0; o >>= 1) s += __shfl_down(s, o, 64);
  if ((tid & 63) == 0) red[tid >> 6] = s;
  __syncthreads();
  const float mu = (red[0] + red[1] + red[2] + red[3]) * (1.f / 1024.f);
  __syncthreads();
  float s2 = 0.f;
#pragma unroll
  for (int j = 0; j < 4; ++j) { const float d = v[j] - mu; s2 += d * d; }
#pragma unroll
  for (int o = 32; o > 0; o >>= 1) s2 += __shfl_down(s2, o, 64);
  if ((tid & 63) == 0) red[tid >> 6] = s2;
  __syncthreads();
  const float rstd = rsqrtf((red[0] + red[1] + red[2] + red[3]) * (1.f / 1024.f) + 1e-5f);

  const float4 gv = *(const float4*)(g + i0);
  const float4 bv = *(const float4*)(be + i0);
  const float o0 = (v[0] - mu) * rstd * gv.x + bv.x;
  const float o1 = (v[1] - mu) * rstd * gv.y + bv.y;
  const float o2 = (v[2] - mu) * rstd * gv.z + bv.z;
  const float o3 = (v[3] - mu) * rstd * gv.w + bv.w;
  if constexpr (OUT_F32) {
    float4 ov; ov.x = o0; ov.y = o1; ov.z = o2; ov.w = o3;
    *(float4*)((float*)outv + base + i0) = ov;
  } else {
    u16x4 ob = { f2bf(o0), f2bf(o1), f2bf(o2), f2bf(o3) };
    *(u16x4*)((ushort_t*)outv + base + i0) = ob;
  }
}

// merged cast: blocks [0,16384) -> x (16M f32); blocks [16384,21504) -> the
// five 1024x1024 weights packed contiguously at dst + 16M.
__global__ __launch_bounds__(256) void cast_all(
    const float* __restrict__ x,
    const float* __restrict__ s0, const float* __restrict__ s1,
    const float* __restrict__ s2, const float* __restrict__ s3,
    const float* __restrict__ s4,
    ushort_t* __restrict__ xdst, ushort_t* __restrict__ wdst)
{
  const int b = blockIdx.x;
  const float* src;
  ushort_t* dst;
  long off;
  if (b < 16384) {
    src = x; dst = xdst; off = (long)b << 10;
  } else {
    const int wi = b - 16384;          // 0..5119, 1024 blocks per weight
    const int w = wi >> 10;
    src = (w == 0) ? s0 : (w == 1) ? s1 : (w == 2) ? s2 : (w == 3) ? s3 : s4;
    dst = wdst + ((long)w << 20);
    off = (long)(wi & 1023) << 10;
  }
  const long i = off + ((long)threadIdx.x << 2);
  const float4 v = *(const float4*)(src + i);
  u16x4 o = { f2bf(v.x), f2bf(v.y), f2bf(v.z), f2bf(v.w) };
  *(u16x4*)(dst + i) = o;
}

// ---------------------------------------------------------------------------
// Memory plan (green since round 2):
//   d_out: [q|k] bf16 -> attb -> final fp32
//   ws R0 (64MiB): [xb|vb] -> S -> [hb|ff1];  R1 (32MiB): vt -> ff2;  R2: weights
// ---------------------------------------------------------------------------
extern "C" void kernel_launch(void* const* d_in, const int* in_sizes, int n_in,
                              void* d_out, int out_size, void* d_ws, size_t ws_size,
                              hipStream_t stream) {
  const int T = 2048, D = 1024;
  const long TD = (long)T * D;
  const long ND = 8 * TD;
  const float* x    = (const float*)d_in[0];
  const float* sit  = (const float*)d_in[1];
  const float* Wq   = (const float*)d_in[2];
  const float* Wk   = (const float*)d_in[3];
  const float* Wv   = (const float*)d_in[4];
  const float* ln1g = (const float*)d_in[5];
  const float* ln1b = (const float*)d_in[6];
  const float* Wf1  = (const float*)d_in[7];
  const float* bf1  = (const float*)d_in[8];
  const float* Wf2  = (const float*)d_in[9];
  const float* bf2  = (const float*)d_in[10];
  const float* ln2g = (const float*)d_in[11];
  const float* ln2b = (const float*)d_in[12];

  ushort_t* W16 = (ushort_t*)d_ws;
  ushort_t* xb  = W16;
  ushort_t* vb  = W16 + ND;
  ushort_t* S   = W16;
  ushort_t* hb  = W16;
  ushort_t* ff1 = W16 + ND;
  ushort_t* vt  = W16 + 2 * ND;
  ushort_t* ff2 = vt;
  ushort_t* wq  = W16 + 3 * ND;      // wq|wk|wv contiguous = fused [3072][1024]
  ushort_t* wf1 = wq + 3L * D * D;
  ushort_t* wf2 = wf1 + (long)D * D;
  ushort_t* qb = (ushort_t*)d_out;
  ushort_t* kb = qb + ND;
  ushort_t* attb = (ushort_t*)d_out;

  cast_all<<<21504, 256, 0, stream>>>(x, Wq, Wk, Wv, Wf1, Wf2, xb, wq);

  // fused QKV: [16384,1024] @ [3072,1024]^T, epilogue routes to qb/kb/vb
  gemm256<0, 2, true><<<dim3(768), 512, 0, stream>>>(
      xb, 1024, wq, 1024, qb, kb, vb, 1024, nullptr, 1.f, 1024);

  transpose_bf16<<<dim3(16, 32, 8), 256, 0, stream>>>(vb, 1024, TD, vt, 2048, TD);

  // scores: S = Q K^T / 32, batch->XCD pinned triangular 256x128 tiles
  gemmA<0, 1, false><<<dim3(576), 512, 0, stream>>>(
      qb, 1024, TD, kb, 1024, TD, S, 2048, (long)T * T, nullptr, 0.03125f, 1024);

  softmax_sit2<<<8192, 256, 0, stream>>>(S, sit);

  // att = P @ V, batch->XCD pinned balanced-pair tiles, K=(by+1)*256
  gemmA<0, 2, true><<<dim3(512), 512, 0, stream>>>(
      S, 2048, (long)T * T, vt, 2048, TD, attb, 1024, TD, nullptr, 1.f, 2048);

  resid_ln<true, false><<<16384, 256, 0, stream>>>(attb, x, ln1g, ln1b, hb);

  gemm256<2, 1, false><<<dim3(4, 64), 512, 0, stream>>>(
      hb, 1024, wf1, 1024, ff1, ff1, ff1, 1024, bf1, 1.f, 1024);
  gemm256<1, 1, false><<<dim3(4, 64), 512, 0, stream>>>(
      ff1, 1024, wf2, 1024, ff2, ff2, ff2, 1024, bf2, 1.f, 1024);

  resid_ln<false, true><<<16384, 256, 0, stream>>>(ff2, hb, ln2g, ln2b, (float*)d_out);
}